// Round 3
// baseline (717.849 us; speedup 1.0000x reference)
//
#include <hip/hip_runtime.h>
#include <float.h>
#include <math.h>

#define NROWS 131072      // B*H*W = 32*64*64
#define KCB   512
#define DDIM  64
#define HWSP  4096        // H*W
#define BCHW  8388608     // 32*64*64*64

// ---------------- kernel 1: distances + encodings + argmin + indices ----------------
// Block: 256 threads, handles 64 rows (one spatial slab, single image b) x all K=512.
// No workspace: wsq computed per k-tile from the staged LDS copy of W.
__global__ __launch_bounds__(256) void vq_main(const float* __restrict__ x,
                                               const float* __restrict__ Wc,
                                               float* __restrict__ dist,
                                               float* __restrict__ enc,
                                               float* __restrict__ idxo) {
    __shared__ float lx[DDIM][64];   // [d][row] — rows contiguous for b128 reads
    __shared__ float lw[DDIM][68];   // [d][k_local], pad 68 keeps rows 16B-aligned
    __shared__ float lxsq[64];
    __shared__ float lwsq[64];

    const int t  = threadIdx.x;
    const int n0 = blockIdx.x * 64;
    const int b  = n0 >> 12;            // n = b*4096 + s ; 64 | 4096 so one b per block
    const int s0 = n0 & (HWSP - 1);

    // stage x tile (transpose NCHW -> [d][row]); global reads contiguous in s
    {
        const int s = t & 63, cq = t >> 6;
        const float* xb = x + (size_t)b * DDIM * HWSP + s0 + s;
#pragma unroll
        for (int it = 0; it < 16; ++it) {
            const int c = it * 4 + cq;
            lx[c][s] = xb[(size_t)c * HWSP];
        }
    }
    __syncthreads();
    if (t < 64) {
        float s = 0.f;
#pragma unroll
        for (int d = 0; d < DDIM; ++d) { const float v = lx[d][t]; s += v * v; }
        lxsq[t] = s;
    }

    const int rg = t >> 4;   // row group: rows rg*4 .. rg*4+3
    const int kg = t & 15;   // k group:   k_local kg*4 .. kg*4+3  (coalesced dist writes)

    float best[4] = {FLT_MAX, FLT_MAX, FLT_MAX, FLT_MAX};
    int   bidx[4] = {0, 0, 0, 0};

    for (int kt = 0; kt < 8; ++kt) {
        __syncthreads();   // prev tile's lw/lwsq reads done (also covers lxsq on kt=0)
        {   // stage W tile [d][k_local]; global reads contiguous in d
            const int d = t & 63, kq0 = t >> 6;
            const float* wb = Wc + (size_t)(kt * 64) * DDIM + d;
#pragma unroll
            for (int it = 0; it < 16; ++it) {
                const int kq = it * 4 + kq0;
                lw[d][kq] = wb[(size_t)kq * DDIM];
            }
        }
        __syncthreads();
        if (t < 64) {   // wsq for this 64-k tile (2-way LDS aliasing only — free)
            float s = 0.f;
#pragma unroll
            for (int d = 0; d < DDIM; ++d) { const float w = lw[d][t]; s += w * w; }
            lwsq[t] = s;
        }
        __syncthreads();

        float acc[4][4] = {};
#pragma unroll 4
        for (int d = 0; d < DDIM; ++d) {
            const float4 xv = *(const float4*)&lx[d][rg * 4];
            const float4 wv = *(const float4*)&lw[d][kg * 4];
            acc[0][0] += xv.x * wv.x; acc[0][1] += xv.x * wv.y; acc[0][2] += xv.x * wv.z; acc[0][3] += xv.x * wv.w;
            acc[1][0] += xv.y * wv.x; acc[1][1] += xv.y * wv.y; acc[1][2] += xv.y * wv.z; acc[1][3] += xv.y * wv.w;
            acc[2][0] += xv.z * wv.x; acc[2][1] += xv.z * wv.y; acc[2][2] += xv.z * wv.z; acc[2][3] += xv.z * wv.w;
            acc[3][0] += xv.w * wv.x; acc[3][1] += xv.w * wv.y; acc[3][2] += xv.w * wv.z; acc[3][3] += xv.w * wv.w;
        }

        const int kbase = kt * 64 + kg * 4;
        const float4 wq = *(const float4*)&lwsq[kg * 4];
        const float4 z4 = make_float4(0.f, 0.f, 0.f, 0.f);
#pragma unroll
        for (int r = 0; r < 4; ++r) {
            const int n = n0 + rg * 4 + r;
            const float xs = lxsq[rg * 4 + r];
            float4 dv;
            dv.x = xs + wq.x - 2.f * acc[r][0];
            dv.y = xs + wq.y - 2.f * acc[r][1];
            dv.z = xs + wq.z - 2.f * acc[r][2];
            dv.w = xs + wq.w - 2.f * acc[r][3];
            *(float4*)&dist[(size_t)n * KCB + kbase] = dv;
            *(float4*)&enc [(size_t)n * KCB + kbase] = z4;
            const float dd[4] = {dv.x, dv.y, dv.z, dv.w};
#pragma unroll
            for (int j = 0; j < 4; ++j) {
                const int kk = kbase + j;
                if (dd[j] < best[r] || (dd[j] == best[r] && kk < bidx[r])) {
                    best[r] = dd[j]; bidx[r] = kk;
                }
            }
        }
    }

    // argmin reduce across the 16 kg-lanes sharing each rg (numpy first-min tie-break)
#pragma unroll
    for (int off = 8; off >= 1; off >>= 1) {
#pragma unroll
        for (int r = 0; r < 4; ++r) {
            const float od = __shfl_xor(best[r], off);
            const int   oi = __shfl_xor(bidx[r], off);
            if (od < best[r] || (od == best[r] && oi < bidx[r])) { best[r] = od; bidx[r] = oi; }
        }
    }

    __syncthreads();   // all enc zero-writes of this block drained before the 1.0 fix-up
    if (kg == 0) {
#pragma unroll
        for (int r = 0; r < 4; ++r) {
            const int n = n0 + rg * 4 + r;
            idxo[n] = (float)bidx[r];
            enc[(size_t)n * KCB + bidx[r]] = 1.0f;
        }
    }
}

// ---------------- kernel 2: quantized (gather + transpose back to NCHW) ----------------
__global__ __launch_bounds__(256) void vq_quant(const float* __restrict__ Wc,
                                                const float* __restrict__ idxf,
                                                float* __restrict__ qout) {
    __shared__ float lq[64][65];   // [row][c], pad 65 -> conflict-free column reads
    __shared__ int   codes[64];

    const int t  = threadIdx.x;
    const int n0 = blockIdx.x * 64;
    const int b  = n0 >> 12;
    const int s0 = n0 & (HWSP - 1);

    if (t < 64) codes[t] = (int)idxf[n0 + t];
    __syncthreads();
    {   // gather codebook rows; coalesced (64 lanes = one 256B row)
        const int c = t & 63, rq = t >> 6;
#pragma unroll
        for (int it = 0; it < 16; ++it) {
            const int r = it * 4 + rq;
            lq[r][c] = Wc[(size_t)codes[r] * DDIM + c];
        }
    }
    __syncthreads();
    {   // write NCHW; contiguous in s
        const int s = t & 63, cq = t >> 6;
        float* qb = qout + (size_t)b * DDIM * HWSP + s0 + s;
#pragma unroll
        for (int it = 0; it < 16; ++it) {
            const int c = it * 4 + cq;
            qb[(size_t)c * HWSP] = lq[s][c];
        }
    }
}

// ---------------- kernel 3: perplexity from indices (single block, LDS hist) ----------------
__global__ __launch_bounds__(512) void vq_perp(const float* __restrict__ idxf,
                                               float* __restrict__ perp) {
    __shared__ unsigned int lh[KCB];
    __shared__ float red[8];
    const int t = threadIdx.x;
    lh[t] = 0u;
    __syncthreads();
    for (int i = t; i < NROWS; i += 512)
        atomicAdd(&lh[(int)idxf[i]], 1u);
    __syncthreads();
    const float p = (float)lh[t] * (1.0f / (float)NROWS);
    float term = p * logf(p + 1e-10f);
#pragma unroll
    for (int off = 32; off >= 1; off >>= 1) term += __shfl_down(term, off);
    if ((t & 63) == 0) red[t >> 6] = term;
    __syncthreads();
    if (t == 0) {
        float s = 0.f;
#pragma unroll
        for (int i = 0; i < 8; ++i) s += red[i];
        *perp = expf(-s);
    }
}

extern "C" void kernel_launch(void* const* d_in, const int* in_sizes, int n_in,
                              void* d_out, int out_size, void* d_ws, size_t ws_size,
                              hipStream_t stream) {
    const float* x  = (const float*)d_in[0];
    const float* Wc = (const float*)d_in[1];

    float* out = (float*)d_out;
    const size_t NK = (size_t)NROWS * KCB;
    float* dist  = out;                 // [N,K]
    float* enc   = out + NK;            // [N,K]
    float* idxo  = out + 2 * NK;        // [N,1] (indices stored as f32)
    float* quant = idxo + NROWS;        // [B,C,H,W]
    float* perp  = quant + (size_t)BCHW;// scalar

    (void)d_ws; (void)ws_size;          // no workspace use — d_out only

    vq_main <<<NROWS / 64, 256, 0, stream>>>(x, Wc, dist, enc, idxo);
    vq_quant<<<NROWS / 64, 256, 0, stream>>>(Wc, idxo, quant);
    vq_perp <<<1,          512, 0, stream>>>(idxo, perp);
}